// Round 11
// baseline (488.398 us; speedup 1.0000x reference)
//
#include <hip/hip_runtime.h>

// HGNN layer, B=4, N=E=4096, D=128, fp32 in/out.
// Round 11: R9 dbuf GEMM re-shaped for cross-block barrier overlap:
// 64x128 tile, 512 thr / 8 waves, grid 512 blocks = 2 blocks/CU.
// Schedule identical to R9 (LDS dbuf, 2 named reg sets, 1 barrier/phase).
// All other kernels identical to R9/R6.

typedef __bf16 bf16;
typedef bf16 bf16x8 __attribute__((ext_vector_type(8)));
typedef float f32x4 __attribute__((ext_vector_type(4)));
typedef unsigned long long u64;

#define LDK 72  // LDS row stride in bf16 elems
#define SWZ(r, c) ((c) ^ ((((r) >> 3) & 7) << 3))
#define CAP 192

union BPack { bf16 h[2]; unsigned int u; };
static __device__ __forceinline__ bf16 tob(float f) { return (bf16)f; }

// ---------------------------------------------------------------------------
// K1: x_w = x @ mlp_W + mlp_b, fused xt = x @ theta.
__global__ __launch_bounds__(256) void mlp_k(const float* __restrict__ x,
                                             const float* __restrict__ W,
                                             const float* __restrict__ bias,
                                             const float* __restrict__ theta,
                                             float* __restrict__ xw,
                                             float* __restrict__ xt) {
    __shared__ float Ws[32][128];
    __shared__ float xs[32][128];
    const int t = threadIdx.x;
    const long r0 = (long)blockIdx.x * 32;

    for (int i = t * 4; i < 4096; i += 1024)
        *(float4*)&xs[i >> 7][i & 127] = *(const float4*)&x[r0 * 128 + i];

    const int d = t & 127;
    const int rg = (t >> 7) * 16;
    float acc[16];
#pragma unroll
    for (int r = 0; r < 16; ++r) acc[r] = 0.f;

    for (int kk = 0; kk < 128; kk += 32) {
        __syncthreads();
        for (int i = t * 4; i < 4096; i += 1024)
            *(float4*)&Ws[i >> 7][i & 127] =
                *(const float4*)&W[(kk + (i >> 7)) * 128 + (i & 127)];
        __syncthreads();
        for (int k = 0; k < 32; ++k) {
            float w = Ws[k][d];
#pragma unroll
            for (int r = 0; r < 16; ++r) acc[r] += xs[rg + r][kk + k] * w;
        }
    }
    const float bd = bias[d];
#pragma unroll
    for (int r = 0; r < 16; ++r)
        xw[(r0 + rg + r) * 128 + d] = acc[r] + bd;

    if (t < 32) {
        float s = 0.f;
        for (int k = 0; k < 128; ++k) s += xs[t][k] * theta[k];
        xt[r0 + t] = s;
    }
}

// ---------------------------------------------------------------------------
// Row bitmask, latency-parallel (R6 proven).
__global__ __launch_bounds__(256) void bmask2_k(const float* __restrict__ inc,
                                                u64* __restrict__ rowmask) {
    const int b = blockIdx.y;
    const int n = blockIdx.x * 4 + (threadIdx.x >> 6);
    const int l = threadIdx.x & 63;
    const float* p = inc + ((long)b << 24) + (long)n * 4096 + l * 64;
    u64 w = 0;
#pragma unroll
    for (int j = 0; j < 16; ++j) {
        const float4 v = *(const float4*)(p + j * 4);
        w |= (u64)(v.x != 0.f ? 1u : 0u) << (4 * j);
        w |= (u64)(v.y != 0.f ? 1u : 0u) << (4 * j + 1);
        w |= (u64)(v.z != 0.f ? 1u : 0u) << (4 * j + 2);
        w |= (u64)(v.w != 0.f ? 1u : 0u) << (4 * j + 3);
    }
    rowmask[((long)b * 4096 + n) * 64 + l] = w;
}

// 64x64 bit-tile transpose (incident masks).
__global__ void btrans_k(const u64* __restrict__ rowmask, u64* __restrict__ colmask) {
    const int tn = blockIdx.x, te = blockIdx.y, b = blockIdx.z;
    const int l = threadIdx.x;
    __shared__ u64 w[64];
    w[l] = rowmask[((long)b * 4096 + tn * 64 + l) * 64 + te];
    __syncthreads();
    u64 o = 0;
#pragma unroll 8
    for (int j = 0; j < 64; ++j) o |= ((w[j] >> l) & 1ull) << j;
    colmask[((long)b * 4096 + te * 64 + l) * 64 + tn] = o;
}

// ---------------------------------------------------------------------------
// ELL list build (R5 proven).
__global__ __launch_bounds__(256) void lists_k(const u64* __restrict__ mask,
                                               ushort* __restrict__ idx,
                                               int* __restrict__ cnts) {
    const int b = blockIdx.y;
    const int r = blockIdx.x * 4 + (threadIdx.x >> 6);
    const int l = threadIdx.x & 63;
    u64 m = mask[((long)b * 4096 + r) * 64 + l];
    const int pc = __popcll(m);
    int pre = pc;
#pragma unroll
    for (int o = 1; o < 64; o <<= 1) {
        int t = __shfl_up(pre, o);
        if (l >= o) pre += t;
    }
    const int total = __shfl(pre, 63);
    if (l == 63) cnts[b * 4096 + r] = total;
    ushort* op = idx + ((long)b * 4096 + r) * CAP;
    int k = pre - pc;
    while (m) {
        const int bit = __builtin_ctzll(m);
        m &= m - 1;
        if (k < CAP) op[k] = (ushort)(l * 64 + bit);
        ++k;
    }
}

// ---------------------------------------------------------------------------
// masked softmax over E per batch.
__global__ void softmax_k(const float* __restrict__ sc, const int* __restrict__ mask,
                          float* __restrict__ attn) {
    const int b = blockIdx.x, t = threadIdx.x;
    __shared__ float red[1024];
    const float* sb = sc + b * 4096;
    const int* mb = mask + b * 4096;

    float mx = -1e30f;
    for (int e = t; e < 4096; e += 1024)
        if (mb[e] != 0) mx = fmaxf(mx, sb[e]);
    red[t] = mx;
    __syncthreads();
    for (int st = 512; st > 0; st >>= 1) {
        if (t < st) red[t] = fmaxf(red[t], red[t + st]);
        __syncthreads();
    }
    mx = red[0];
    __syncthreads();

    float sum = 0.f;
    for (int e = t; e < 4096; e += 1024)
        if (mb[e] != 0) sum += expf(sb[e] - mx);
    red[t] = sum;
    __syncthreads();
    for (int st = 512; st > 0; st >>= 1) {
        if (t < st) red[t] += red[t + st];
        __syncthreads();
    }
    const float inv = 1.f / red[0];
    for (int e = t; e < 4096; e += 1024)
        attn[b * 4096 + e] = (mb[e] != 0) ? expf(sb[e] - mx) * inv : 0.f;
}

// ---------------------------------------------------------------------------
// ELL gather (R5 proven, unchanged).
template <int PAIR, bool SCALE, bool ADDEPS, bool HXT, bool EPI>
__global__ __launch_bounds__(256) void gatherE_k(
    const ushort* __restrict__ idx, const int* __restrict__ cnts,
    const u64* __restrict__ mask, const float* __restrict__ src,
    const float* __restrict__ src2, const float* __restrict__ attn,
    const float* __restrict__ xt, const float* __restrict__ epsp,
    const float* __restrict__ bng, const float* __restrict__ bnb,
    const float* __restrict__ bnm, const float* __restrict__ bnv,
    float* __restrict__ out, float* __restrict__ hxt) {
    const int b = blockIdx.y;
    const int r = blockIdx.x * 4 + (threadIdx.x >> 6);
    const int l = threadIdx.x & 63;
    const long rowid = (long)b * 4096 + r;
    const int cnt = cnts[rowid];
    const ushort* ip = idx + rowid * CAP;
    const float* S = src + (long)b * 524288;
    const float* S2 = ADDEPS ? (src2 + (long)b * 524288) : nullptr;
    const float* ab = attn + (long)b * 4096;
    const float* xb = xt + (long)b * 4096;
    const float eps_v = ADDEPS ? epsp[0] : 0.f;
    const int c0 = 2 * l;

    float a0x = 0.f, a0y = 0.f, a1x = 0.f, a1y = 0.f;
    float a2x = 0.f, a2y = 0.f, a3x = 0.f, a3y = 0.f;
    float hacc = 0.f;

    auto edge1 = [&](int e) {
        float2 v = *(const float2*)(S + (long)e * 128 + c0);
        if (PAIR == 2) {
            float2 w = *(const float2*)(S + 2097152 + (long)e * 128 + c0);
            v.x += w.x; v.y += w.y;
        }
        if (ADDEPS) {
            float2 u = *(const float2*)(S2 + (long)e * 128 + c0);
            v.x += eps_v * u.x; v.y += eps_v * u.y;
        }
        if (SCALE) {
            const float s = ab[e];
            v.x *= s; v.y *= s;
        }
        if (HXT) hacc += xb[e];
        a0x += v.x; a0y += v.y;
    };

    const int n = cnt < CAP ? cnt : CAP;
    int i = 0;
    for (; i + 4 <= n; i += 4) {
        const int e0 = ip[i], e1 = ip[i + 1], e2 = ip[i + 2], e3 = ip[i + 3];
        float2 v0 = *(const float2*)(S + (long)e0 * 128 + c0);
        float2 v1 = *(const float2*)(S + (long)e1 * 128 + c0);
        float2 v2 = *(const float2*)(S + (long)e2 * 128 + c0);
        float2 v3 = *(const float2*)(S + (long)e3 * 128 + c0);
        if (PAIR == 2) {
            float2 w0 = *(const float2*)(S + 2097152 + (long)e0 * 128 + c0);
            float2 w1 = *(const float2*)(S + 2097152 + (long)e1 * 128 + c0);
            float2 w2 = *(const float2*)(S + 2097152 + (long)e2 * 128 + c0);
            float2 w3 = *(const float2*)(S + 2097152 + (long)e3 * 128 + c0);
            v0.x += w0.x; v0.y += w0.y; v1.x += w1.x; v1.y += w1.y;
            v2.x += w2.x; v2.y += w2.y; v3.x += w3.x; v3.y += w3.y;
        }
        if (ADDEPS) {
            float2 u0 = *(const float2*)(S2 + (long)e0 * 128 + c0);
            float2 u1 = *(const float2*)(S2 + (long)e1 * 128 + c0);
            float2 u2 = *(const float2*)(S2 + (long)e2 * 128 + c0);
            float2 u3 = *(const float2*)(S2 + (long)e3 * 128 + c0);
            v0.x += eps_v * u0.x; v0.y += eps_v * u0.y;
            v1.x += eps_v * u1.x; v1.y += eps_v * u1.y;
            v2.x += eps_v * u2.x; v2.y += eps_v * u2.y;
            v3.x += eps_v * u3.x; v3.y += eps_v * u3.y;
        }
        if (SCALE) {
            const float s0 = ab[e0], s1 = ab[e1], s2 = ab[e2], s3 = ab[e3];
            v0.x *= s0; v0.y *= s0; v1.x *= s1; v1.y *= s1;
            v2.x *= s2; v2.y *= s2; v3.x *= s3; v3.y *= s3;
        }
        if (HXT) hacc += (xb[e0] + xb[e1]) + (xb[e2] + xb[e3]);
        a0x += v0.x; a0y += v0.y; a1x += v1.x; a1y += v1.y;
        a2x += v2.x; a2y += v2.y; a3x += v3.x; a3y += v3.y;
    }
    for (; i < n; ++i) edge1(ip[i]);

    if (cnt > CAP) {  // astronomically rare; exact fallback
        const u64 wrd = mask[rowid * 64 + l];
        int seen = 0;
        for (int wi = 0; wi < 64; ++wi) {
            u64 m = __shfl(wrd, wi);
            const int pc = __popcll(m);
            if (seen + pc > CAP) {
                int tk = CAP - seen;
                if (tk < 0) tk = 0;
                for (int t = 0; t < tk; ++t) m &= m - 1;
                while (m) {
                    const int bit = __builtin_ctzll(m);
                    m &= m - 1;
                    edge1((wi << 6) + bit);
                }
            }
            seen += pc;
        }
    }

    float ax = (a0x + a1x) + (a2x + a3x);
    float ay = (a0y + a1y) + (a2y + a3y);
    if (EPI) {
        float t0 = (ax >= 0.f) ? ax : 0.01f * ax;
        float t1 = (ay >= 0.f) ? ay : 0.01f * ay;
        ax = (t0 - bnm[c0]) * rsqrtf(bnv[c0] + 1e-5f) * bng[c0] + bnb[c0];
        ay = (t1 - bnm[c0 + 1]) * rsqrtf(bnv[c0 + 1] + 1e-5f) * bng[c0 + 1] + bnb[c0 + 1];
    }
    *(float2*)&out[(long)b * 524288 + (long)r * 128 + c0] = (float2){ax, ay};
    if (HXT && l == 0) hxt[rowid] = hacc;
}

// ---------------------------------------------------------------------------
// Dense bf16-MFMA GEMM, 64x128 tile, 512 thr = 8 waves (wave owns 16x64),
// BK=64, LDS double-buffered (R9 schedule), 2 blocks/CU for cross-block
// barrier overlap. grid (64, KS, 4).
template <int KS>
__global__ __launch_bounds__(512, 4) void gemm_dense(
    const float* __restrict__ A, const float* __restrict__ Bsrc,
    float* __restrict__ P) {
    __shared__ __align__(16) bf16 As[2][64][LDK];
    __shared__ __align__(16) bf16 Bs[2][128][LDK];

    const int tid = threadIdx.x;
    const int m0 = blockIdx.x * 64;
    const int ksi = blockIdx.y;
    const int b = blockIdx.z;
    constexpr int KCH = 4096 / KS;
    const int kbeg = ksi * KCH, kend = kbeg + KCH;
    const long Aoff = (long)b << 24;
    const long Boff = (long)b * 524288;

    const int wave = tid >> 6, lane = tid & 63;
    const int lr = lane & 15, kb = lane >> 4;
    const int wm = (wave >> 1) * 16, wn = (wave & 1) * 64;

    // staging decomposition
    const int ar = tid >> 3, ak = (tid & 7) * 8;        // A: row 0..63, 8 k
    const int bd4 = (tid & 31) * 4, bk = (tid >> 5) * 4; // B: 4 d, 4 k-rows

    const float* Abase = A + Aoff + (long)(m0 + ar) * 4096 + ak;
    const float* Bbase = Bsrc + Boff + bd4;

    f32x4 acc[4];
#pragma unroll
    for (int nf = 0; nf < 4; ++nf) acc[nf] = (f32x4){0.f, 0.f, 0.f, 0.f};

    // two named register sets
    float4 a0_A, a1_A, a0_B, a1_B;
    float4 b0_A, b1_A, b2_A, b3_A, b0_B, b1_B, b2_B, b3_B;

#define GLOAD(S, kk)                                                        \
    {                                                                       \
        const float* gb = Bbase + (long)((kk) + bk) * 128;                  \
        b0_##S = *(const float4*)gb;                                        \
        b1_##S = *(const float4*)(gb + 128);                                \
        b2_##S = *(const float4*)(gb + 256);                                \
        b3_##S = *(const float4*)(gb + 384);                                \
        const float* ga = Abase + (kk);                                     \
        a0_##S = *(const float4*)ga;                                        \
        a1_##S = *(const float4*)(ga + 4);                                  \
    }

#define STAGE(S, bu)                                                        \
    {                                                                       \
        bf16x8 p;                                                           \
        p[0] = tob(a0_##S.x); p[1] = tob(a0_##S.y); p[2] = tob(a0_##S.z); p[3] = tob(a0_##S.w); \
        p[4] = tob(a1_##S.x); p[5] = tob(a1_##S.y); p[6] = tob(a1_##S.z); p[7] = tob(a1_##S.w); \
        *(bf16x8*)&As[bu][ar][SWZ(ar, ak)] = p;                             \
        float r0[4] = {b0_##S.x, b0_##S.y, b0_##S.z, b0_##S.w};             \
        float r1[4] = {b1_##S.x, b1_##S.y, b1_##S.z, b1_##S.w};             \
        float r2[4] = {b2_##S.x, b2_##S.y, b2_##S.z, b2_##S.w};             \
        float r3[4] = {b3_##S.x, b3_##S.y, b3_##S.z, b3_##S.w};             \
        _Pragma("unroll")                                                   \
        for (int j = 0; j < 4; ++j) {                                       \
            const int d = bd4 + j;                                          \
            BPack q01; q01.h[0] = tob(r0[j]); q01.h[1] = tob(r1[j]);        \
            *(unsigned int*)&Bs[bu][d][SWZ(d, bk)] = q01.u;                 \
            BPack q23; q23.h[0] = tob(r2[j]); q23.h[1] = tob(r3[j]);        \
            *(unsigned int*)&Bs[bu][d][SWZ(d, bk + 2)] = q23.u;             \
        }                                                                   \
    }

#define MFMA_STEP(bu)                                                       \
    {                                                                       \
        _Pragma("unroll")                                                   \
        for (int ks = 0; ks < 2; ++ks) {                                    \
            const int ka = ks * 32 + kb * 8;                                \
            const int rA = wm + lr;                                         \
            bf16x8 af = *(const bf16x8*)&As[bu][rA][SWZ(rA, ka)];           \
            _Pragma("unroll")                                               \
            for (int nf = 0; nf < 4; ++nf) {                                \
                const int rB = wn + nf * 16 + lr;                           \
                bf16x8 bfr = *(const bf16x8*)&Bs[bu][rB][SWZ(rB, ka)];      \
                acc[nf] = __builtin_amdgcn_mfma_f32_16x16x32_bf16(          \
                    af, bfr, acc[nf], 0, 0, 0);                             \
            }                                                               \
        }                                                                   \
    }

    // prologue
    GLOAD(A, kbeg);
    GLOAD(B, kbeg + 64);
    STAGE(A, 0);
    __syncthreads();

    // KCH % 128 == 0 -> clean 2-phase iterations, no tail.
    for (int kk = kbeg; kk < kend; kk += 128) {
        MFMA_STEP(0);
        STAGE(B, 1);
        if (kk + 128 < kend) GLOAD(A, kk + 128);
        __syncthreads();
        MFMA_STEP(1);
        if (kk + 128 < kend) {
            STAGE(A, 0);
            if (kk + 192 < kend) GLOAD(B, kk + 192);
            __syncthreads();
        }
    }
#undef GLOAD
#undef STAGE
#undef MFMA_STEP

    float* Cp = P + (long)(ksi * 4 + b) * 524288;
    const int rb = m0 + wm + kb * 4;
#pragma unroll
    for (int nf = 0; nf < 4; ++nf) {
        const int col = wn + nf * 16 + lr;
#pragma unroll
        for (int i = 0; i < 4; ++i)
            Cp[(long)(rb + i) * 128 + col] = acc[nf][i];
    }
}

// ---------------------------------------------------------------------------
template <int KS>
static void run_all(const float* incident, const float* degree_v, const float* degree_e,
                    const float* x, const int* e_masks, const float* mlp_W,
                    const float* mlp_b, const float* theta, const float* epsp,
                    const float* bng, const float* bnb, const float* bnm,
                    const float* bnv, float* out, float* ws, hipStream_t stream) {
    float* xw  = ws;                        // 2M floats
    float* hxw = ws + 2097152;              // 2M
    float* t1  = ws + 4194304;              // 2M
    float* Pd  = ws + 6291456;              // KS*2M
    float* tail = Pd + (long)KS * 2097152;
    u64* rowmask = (u64*)tail;                      // 1M u64
    u64* colmask = rowmask + 1048576;               // 1M u64
    ushort* rowidx = (ushort*)(colmask + 1048576);  // 16384*CAP u16
    ushort* colidx = rowidx + 16384 * CAP;
    int* rowcnt = (int*)(colidx + 16384 * CAP);     // 16K int
    int* colcnt = rowcnt + 16384;
    float* xt  = (float*)(colcnt + 16384);
    float* hxt = xt + 16384;
    float* att = hxt + 16384;

    mlp_k<<<512, 256, 0, stream>>>(x, mlp_W, mlp_b, theta, xw, xt);
    bmask2_k<<<dim3(1024, 4), 256, 0, stream>>>(incident, rowmask);
    btrans_k<<<dim3(64, 64, 4), 64, 0, stream>>>(rowmask, colmask);
    lists_k<<<dim3(1024, 4), 256, 0, stream>>>(rowmask, rowidx, rowcnt);
    lists_k<<<dim3(1024, 4), 256, 0, stream>>>(colmask, colidx, colcnt);

    const dim3 gG(1024, 4);
    // G1: hxw = Ht @ xw  (+ hxt = Ht @ xt)
    gatherE_k<1, false, false, true, false><<<gG, 256, 0, stream>>>(
        colidx, colcnt, colmask, xw, nullptr, att, xt, nullptr,
        nullptr, nullptr, nullptr, nullptr, hxw, hxt);
    softmax_k<<<4, 1024, 0, stream>>>(hxt, e_masks, att);
    // G2: t1 = incident @ (attn * hxw)
    gatherE_k<1, true, false, false, false><<<gG, 256, 0, stream>>>(
        rowidx, rowcnt, rowmask, hxw, nullptr, att, xt, nullptr,
        nullptr, nullptr, nullptr, nullptr, t1, nullptr);
    // G3: Pd = degree_v @ t1
    gemm_dense<KS><<<dim3(64, KS, 4), 512, 0, stream>>>(degree_v, t1, Pd);
    // G4: t1 = Ht @ sum(Pd)
    gatherE_k<KS, false, false, false, false><<<gG, 256, 0, stream>>>(
        colidx, colcnt, colmask, Pd, nullptr, att, xt, nullptr,
        nullptr, nullptr, nullptr, nullptr, t1, nullptr);
    // G5: Pd = degree_e @ t1
    gemm_dense<KS><<<dim3(64, KS, 4), 512, 0, stream>>>(degree_e, t1, Pd);
    // G6: out = BN(leaky(incident @ (sum(Pd) + eps*hxw)))
    gatherE_k<KS, false, true, false, true><<<gG, 256, 0, stream>>>(
        rowidx, rowcnt, rowmask, Pd, hxw, att, xt, epsp,
        bng, bnb, bnm, bnv, out, nullptr);
}

extern "C" void kernel_launch(void* const* d_in, const int* in_sizes, int n_in,
                              void* d_out, int out_size, void* d_ws, size_t ws_size,
                              hipStream_t stream) {
    const float* incident = (const float*)d_in[0];
    const float* degree_v = (const float*)d_in[1];
    const float* degree_e = (const float*)d_in[2];
    const float* x        = (const float*)d_in[3];
    const int*   e_masks  = (const int*)d_in[4];
    const float* mlp_W    = (const float*)d_in[5];
    const float* mlp_b    = (const float*)d_in[6];
    const float* theta    = (const float*)d_in[7];
    const float* epsp     = (const float*)d_in[8];
    const float* bng      = (const float*)d_in[9];
    const float* bnb      = (const float*)d_in[10];
    const float* bnm      = (const float*)d_in[11];
    const float* bnv      = (const float*)d_in[12];
    float* out = (float*)d_out;
    float* ws = (float*)d_ws;

    if (ws_size >= 80000000ull)
        run_all<2>(incident, degree_v, degree_e, x, e_masks, mlp_W, mlp_b, theta,
                   epsp, bng, bnb, bnm, bnv, out, ws, stream);
    else
        run_all<1>(incident, degree_v, degree_e, x, e_masks, mlp_W, mlp_b, theta,
                   epsp, bng, bnb, bnm, bnv, out, ws, stream);
}

// Round 12
// 431.123 us; speedup vs baseline: 1.1328x; 1.1328x over previous
//
#include <hip/hip_runtime.h>

// HGNN layer, B=4, N=E=4096, D=128, fp32 in/out.
// Round 12: attack the non-GEMM stack (~2/3 of runtime per R8-subtraction):
//  - XCD-affinity swizzle: batch b -> XCD pair (slot=bid&7, b=slot>>1) for
//    gathers AND gemm, so each XCD L2 caches only its batch's 2MB panel.
//  - pairsum_k: pre-sum split-K partials (4MB -> 2MB per batch) so G4/G6
//    gathers read a single panel (PAIR removed).
// GEMM internals = R9 (best measured, ~80us each). Everything else R6.

typedef __bf16 bf16;
typedef bf16 bf16x8 __attribute__((ext_vector_type(8)));
typedef float f32x4 __attribute__((ext_vector_type(4)));
typedef unsigned long long u64;

#define LDK 72  // LDS row stride in bf16 elems
#define SWZ(r, c) ((c) ^ ((((r) >> 3) & 7) << 3))
#define CAP 192

union BPack { bf16 h[2]; unsigned int u; };
static __device__ __forceinline__ bf16 tob(float f) { return (bf16)f; }

// ---------------------------------------------------------------------------
// K1: x_w = x @ mlp_W + mlp_b, fused xt = x @ theta.
__global__ __launch_bounds__(256) void mlp_k(const float* __restrict__ x,
                                             const float* __restrict__ W,
                                             const float* __restrict__ bias,
                                             const float* __restrict__ theta,
                                             float* __restrict__ xw,
                                             float* __restrict__ xt) {
    __shared__ float Ws[32][128];
    __shared__ float xs[32][128];
    const int t = threadIdx.x;
    const long r0 = (long)blockIdx.x * 32;

    for (int i = t * 4; i < 4096; i += 1024)
        *(float4*)&xs[i >> 7][i & 127] = *(const float4*)&x[r0 * 128 + i];

    const int d = t & 127;
    const int rg = (t >> 7) * 16;
    float acc[16];
#pragma unroll
    for (int r = 0; r < 16; ++r) acc[r] = 0.f;

    for (int kk = 0; kk < 128; kk += 32) {
        __syncthreads();
        for (int i = t * 4; i < 4096; i += 1024)
            *(float4*)&Ws[i >> 7][i & 127] =
                *(const float4*)&W[(kk + (i >> 7)) * 128 + (i & 127)];
        __syncthreads();
        for (int k = 0; k < 32; ++k) {
            float w = Ws[k][d];
#pragma unroll
            for (int r = 0; r < 16; ++r) acc[r] += xs[rg + r][kk + k] * w;
        }
    }
    const float bd = bias[d];
#pragma unroll
    for (int r = 0; r < 16; ++r)
        xw[(r0 + rg + r) * 128 + d] = acc[r] + bd;

    if (t < 32) {
        float s = 0.f;
        for (int k = 0; k < 128; ++k) s += xs[t][k] * theta[k];
        xt[r0 + t] = s;
    }
}

// ---------------------------------------------------------------------------
// Row bitmask, latency-parallel (R6 proven).
__global__ __launch_bounds__(256) void bmask2_k(const float* __restrict__ inc,
                                                u64* __restrict__ rowmask) {
    const int b = blockIdx.y;
    const int n = blockIdx.x * 4 + (threadIdx.x >> 6);
    const int l = threadIdx.x & 63;
    const float* p = inc + ((long)b << 24) + (long)n * 4096 + l * 64;
    u64 w = 0;
#pragma unroll
    for (int j = 0; j < 16; ++j) {
        const float4 v = *(const float4*)(p + j * 4);
        w |= (u64)(v.x != 0.f ? 1u : 0u) << (4 * j);
        w |= (u64)(v.y != 0.f ? 1u : 0u) << (4 * j + 1);
        w |= (u64)(v.z != 0.f ? 1u : 0u) << (4 * j + 2);
        w |= (u64)(v.w != 0.f ? 1u : 0u) << (4 * j + 3);
    }
    rowmask[((long)b * 4096 + n) * 64 + l] = w;
}

// 64x64 bit-tile transpose (incident masks).
__global__ void btrans_k(const u64* __restrict__ rowmask, u64* __restrict__ colmask) {
    const int tn = blockIdx.x, te = blockIdx.y, b = blockIdx.z;
    const int l = threadIdx.x;
    __shared__ u64 w[64];
    w[l] = rowmask[((long)b * 4096 + tn * 64 + l) * 64 + te];
    __syncthreads();
    u64 o = 0;
#pragma unroll 8
    for (int j = 0; j < 64; ++j) o |= ((w[j] >> l) & 1ull) << j;
    colmask[((long)b * 4096 + te * 64 + l) * 64 + tn] = o;
}

// ---------------------------------------------------------------------------
// ELL list build (R5 proven).
__global__ __launch_bounds__(256) void lists_k(const u64* __restrict__ mask,
                                               ushort* __restrict__ idx,
                                               int* __restrict__ cnts) {
    const int b = blockIdx.y;
    const int r = blockIdx.x * 4 + (threadIdx.x >> 6);
    const int l = threadIdx.x & 63;
    u64 m = mask[((long)b * 4096 + r) * 64 + l];
    const int pc = __popcll(m);
    int pre = pc;
#pragma unroll
    for (int o = 1; o < 64; o <<= 1) {
        int t = __shfl_up(pre, o);
        if (l >= o) pre += t;
    }
    const int total = __shfl(pre, 63);
    if (l == 63) cnts[b * 4096 + r] = total;
    ushort* op = idx + ((long)b * 4096 + r) * CAP;
    int k = pre - pc;
    while (m) {
        const int bit = __builtin_ctzll(m);
        m &= m - 1;
        if (k < CAP) op[k] = (ushort)(l * 64 + bit);
        ++k;
    }
}

// ---------------------------------------------------------------------------
// masked softmax over E per batch.
__global__ void softmax_k(const float* __restrict__ sc, const int* __restrict__ mask,
                          float* __restrict__ attn) {
    const int b = blockIdx.x, t = threadIdx.x;
    __shared__ float red[1024];
    const float* sb = sc + b * 4096;
    const int* mb = mask + b * 4096;

    float mx = -1e30f;
    for (int e = t; e < 4096; e += 1024)
        if (mb[e] != 0) mx = fmaxf(mx, sb[e]);
    red[t] = mx;
    __syncthreads();
    for (int st = 512; st > 0; st >>= 1) {
        if (t < st) red[t] = fmaxf(red[t], red[t + st]);
        __syncthreads();
    }
    mx = red[0];
    __syncthreads();

    float sum = 0.f;
    for (int e = t; e < 4096; e += 1024)
        if (mb[e] != 0) sum += expf(sb[e] - mx);
    red[t] = sum;
    __syncthreads();
    for (int st = 512; st > 0; st >>= 1) {
        if (t < st) red[t] += red[t + st];
        __syncthreads();
    }
    const float inv = 1.f / red[0];
    for (int e = t; e < 4096; e += 1024)
        attn[b * 4096 + e] = (mb[e] != 0) ? expf(sb[e] - mx) * inv : 0.f;
}

// ---------------------------------------------------------------------------
// Pair-sum of split-K partials: O[b][i] = P[ksi=0][b][i] + P[ksi=1][b][i].
__global__ __launch_bounds__(256) void pairsum_k(const float* __restrict__ P,
                                                 float* __restrict__ O) {
    const long i4 = (long)blockIdx.x * 256 + threadIdx.x;  // 0..524287 float4
    float4 a = ((const float4*)P)[i4];
    float4 c = ((const float4*)P)[i4 + 524288];  // +2097152 floats
    a.x += c.x; a.y += c.y; a.z += c.z; a.w += c.w;
    ((float4*)O)[i4] = a;
}

// ---------------------------------------------------------------------------
// ELL gather, XCD-affinity swizzled: grid 4096 1D; slot=bid&7 -> batch=slot>>1
// so each batch's blocks land on one XCD pair (L2-resident src panel).
// out[r,:] = sum_e src[e,:] [+ eps*src2[e,:]] [* attn[e]]; HXT/EPI as before.
template <bool SCALE, bool ADDEPS, bool HXT, bool EPI>
__global__ __launch_bounds__(256) void gatherE_k(
    const ushort* __restrict__ idx, const int* __restrict__ cnts,
    const u64* __restrict__ mask, const float* __restrict__ src,
    const float* __restrict__ src2, const float* __restrict__ attn,
    const float* __restrict__ xt, const float* __restrict__ epsp,
    const float* __restrict__ bng, const float* __restrict__ bnb,
    const float* __restrict__ bnm, const float* __restrict__ bnv,
    float* __restrict__ out, float* __restrict__ hxt) {
    const int bid = blockIdx.x;
    const int slot = bid & 7;
    const int b = slot >> 1;                          // batch -> XCD pair
    const int chunk = (bid >> 3) * 2 + (slot & 1);    // 0..1023
    const int r = chunk * 4 + (threadIdx.x >> 6);
    const int l = threadIdx.x & 63;
    const long rowid = (long)b * 4096 + r;
    const int cnt = cnts[rowid];
    const ushort* ip = idx + rowid * CAP;
    const float* S = src + (long)b * 524288;
    const float* S2 = ADDEPS ? (src2 + (long)b * 524288) : nullptr;
    const float* ab = attn + (long)b * 4096;
    const float* xb = xt + (long)b * 4096;
    const float eps_v = ADDEPS ? epsp[0] : 0.f;
    const int c0 = 2 * l;

    float a0x = 0.f, a0y = 0.f, a1x = 0.f, a1y = 0.f;
    float a2x = 0.f, a2y = 0.f, a3x = 0.f, a3y = 0.f;
    float hacc = 0.f;

    auto edge1 = [&](int e) {
        float2 v = *(const float2*)(S + (long)e * 128 + c0);
        if (ADDEPS) {
            float2 u = *(const float2*)(S2 + (long)e * 128 + c0);
            v.x += eps_v * u.x; v.y += eps_v * u.y;
        }
        if (SCALE) {
            const float s = ab[e];
            v.x *= s; v.y *= s;
        }
        if (HXT) hacc += xb[e];
        a0x += v.x; a0y += v.y;
    };

    const int n = cnt < CAP ? cnt : CAP;
    int i = 0;
    for (; i + 4 <= n; i += 4) {
        const int e0 = ip[i], e1 = ip[i + 1], e2 = ip[i + 2], e3 = ip[i + 3];
        float2 v0 = *(const float2*)(S + (long)e0 * 128 + c0);
        float2 v1 = *(const float2*)(S + (long)e1 * 128 + c0);
        float2 v2 = *(const float2*)(S + (long)e2 * 128 + c0);
        float2 v3 = *(const float2*)(S + (long)e3 * 128 + c0);
        if (ADDEPS) {
            float2 u0 = *(const float2*)(S2 + (long)e0 * 128 + c0);
            float2 u1 = *(const float2*)(S2 + (long)e1 * 128 + c0);
            float2 u2 = *(const float2*)(S2 + (long)e2 * 128 + c0);
            float2 u3 = *(const float2*)(S2 + (long)e3 * 128 + c0);
            v0.x += eps_v * u0.x; v0.y += eps_v * u0.y;
            v1.x += eps_v * u1.x; v1.y += eps_v * u1.y;
            v2.x += eps_v * u2.x; v2.y += eps_v * u2.y;
            v3.x += eps_v * u3.x; v3.y += eps_v * u3.y;
        }
        if (SCALE) {
            const float s0 = ab[e0], s1 = ab[e1], s2 = ab[e2], s3 = ab[e3];
            v0.x *= s0; v0.y *= s0; v1.x *= s1; v1.y *= s1;
            v2.x *= s2; v2.y *= s2; v3.x *= s3; v3.y *= s3;
        }
        if (HXT) hacc += (xb[e0] + xb[e1]) + (xb[e2] + xb[e3]);
        a0x += v0.x; a0y += v0.y; a1x += v1.x; a1y += v1.y;
        a2x += v2.x; a2y += v2.y; a3x += v3.x; a3y += v3.y;
    }
    for (; i < n; ++i) edge1(ip[i]);

    if (cnt > CAP) {  // astronomically rare; exact fallback
        const u64 wrd = mask[rowid * 64 + l];
        int seen = 0;
        for (int wi = 0; wi < 64; ++wi) {
            u64 m = __shfl(wrd, wi);
            const int pc = __popcll(m);
            if (seen + pc > CAP) {
                int tk = CAP - seen;
                if (tk < 0) tk = 0;
                for (int t = 0; t < tk; ++t) m &= m - 1;
                while (m) {
                    const int bit = __builtin_ctzll(m);
                    m &= m - 1;
                    edge1((wi << 6) + bit);
                }
            }
            seen += pc;
        }
    }

    float ax = (a0x + a1x) + (a2x + a3x);
    float ay = (a0y + a1y) + (a2y + a3y);
    if (EPI) {
        float t0 = (ax >= 0.f) ? ax : 0.01f * ax;
        float t1 = (ay >= 0.f) ? ay : 0.01f * ay;
        ax = (t0 - bnm[c0]) * rsqrtf(bnv[c0] + 1e-5f) * bng[c0] + bnb[c0];
        ay = (t1 - bnm[c0 + 1]) * rsqrtf(bnv[c0 + 1] + 1e-5f) * bng[c0 + 1] + bnb[c0 + 1];
    }
    *(float2*)&out[(long)b * 524288 + (long)r * 128 + c0] = (float2){ax, ay};
    if (HXT && l == 0) hxt[rowid] = hacc;
}

// ---------------------------------------------------------------------------
// Dense bf16-MFMA GEMM (R9 structure): 128x128 tile, 1024 thr = 16 waves,
// BK=64, LDS dbuf, 2 named reg sets, 1 barrier/phase. XCD-affinity 1D grid:
// batch = (bid&7)>>1 so B-panel is XCD-L2-resident. grid = 32*KS*4 blocks.
template <int KS>
__global__ __launch_bounds__(1024, 4) void gemm_dense(
    const float* __restrict__ A, const float* __restrict__ Bsrc,
    float* __restrict__ P) {
    __shared__ __align__(16) bf16 As[2][128][LDK];
    __shared__ __align__(16) bf16 Bs[2][128][LDK];

    const int tid = threadIdx.x;
    const int bid = blockIdx.x;
    const int slot = bid & 7;
    const int b = slot >> 1;                         // batch -> XCD pair
    const int sub = (bid >> 3) * 2 + (slot & 1);     // 0 .. 32*KS-1
    const int ksi = sub % KS;
    const int m0 = (sub / KS) * 128;
    constexpr int KCH = 4096 / KS;
    const int kbeg = ksi * KCH, kend = kbeg + KCH;
    const long Aoff = (long)b << 24;
    const long Boff = (long)b * 524288;

    const int wave = tid >> 6, lane = tid & 63;
    const int lr = lane & 15, kb = lane >> 4;
    const int wm = (wave >> 2) * 32, wn = (wave & 3) * 32;

    const int ar = tid >> 3, ak = (tid & 7) * 8;
    const int bd4 = (tid & 31) * 4, bk2 = (tid >> 5) * 2;

    const float* Abase = A + Aoff + (long)(m0 + ar) * 4096 + ak;
    const float* Bbase = Bsrc + Boff + (long)bk2 * 128 + bd4;

    f32x4 acc[2][2];
#pragma unroll
    for (int mf = 0; mf < 2; ++mf)
#pragma unroll
        for (int nf = 0; nf < 2; ++nf) acc[mf][nf] = (f32x4){0.f, 0.f, 0.f, 0.f};

    float4 pa0A, pa1A, pb0A, pb1A;   // register set A
    float4 pa0B, pa1B, pb0B, pb1B;   // register set B

#define GLOAD(S, kk)                                                        \
    {                                                                       \
        const float* ga = Abase + (kk);                                     \
        pa0##S = *(const float4*)ga;                                        \
        pa1##S = *(const float4*)(ga + 4);                                  \
        const float* gb = Bbase + (long)(kk) * 128;                         \
        pb0##S = *(const float4*)gb;                                        \
        pb1##S = *(const float4*)(gb + 128);                                \
    }

#define STAGE(S, bu)                                                        \
    {                                                                       \
        bf16x8 p;                                                           \
        p[0] = tob(pa0##S.x); p[1] = tob(pa0##S.y); p[2] = tob(pa0##S.z); p[3] = tob(pa0##S.w); \
        p[4] = tob(pa1##S.x); p[5] = tob(pa1##S.y); p[6] = tob(pa1##S.z); p[7] = tob(pa1##S.w); \
        *(bf16x8*)&As[bu][ar][SWZ(ar, ak)] = p;                             \
        float va[4] = {pb0##S.x, pb0##S.y, pb0##S.z, pb0##S.w};             \
        float vb[4] = {pb1##S.x, pb1##S.y, pb1##S.z, pb1##S.w};             \
        _Pragma("unroll")                                                   \
        for (int j = 0; j < 4; ++j) {                                       \
            BPack q; q.h[0] = tob(va[j]); q.h[1] = tob(vb[j]);              \
            *(unsigned int*)&Bs[bu][bd4 + j][SWZ(bd4 + j, bk2)] = q.u;      \
        }                                                                   \
    }

#define MFMA_STEP(bu)                                                       \
    {                                                                       \
        _Pragma("unroll")                                                   \
        for (int ks = 0; ks < 2; ++ks) {                                    \
            const int ka = ks * 32 + kb * 8;                                \
            bf16x8 af[2], bfr[2];                                           \
            _Pragma("unroll")                                               \
            for (int mf = 0; mf < 2; ++mf) {                                \
                const int rA = wm + mf * 16 + lr;                           \
                af[mf] = *(const bf16x8*)&As[bu][rA][SWZ(rA, ka)];          \
            }                                                               \
            _Pragma("unroll")                                               \
            for (int nf = 0; nf < 2; ++nf) {                                \
                const int rB = wn + nf * 16 + lr;                           \
                bfr[nf] = *(const bf16x8*)&Bs[bu][rB][SWZ(rB, ka)];         \
            }                                                               \
            _Pragma("unroll")                                               \
            for (int mf = 0; mf < 2; ++mf)                                  \
                _Pragma("unroll")                                           \
                for (int nf = 0; nf < 2; ++nf)                              \
                    acc[mf][nf] = __builtin_amdgcn_mfma_f32_16x16x32_bf16(  \
                        af[mf], bfr[nf], acc[mf][nf], 0, 0, 0);             \
        }                                                                   \
    }

    GLOAD(A, kbeg);
    GLOAD(B, kbeg + 64);
    STAGE(A, 0);
    __syncthreads();

    for (int kk = kbeg; kk < kend; kk += 128) {
        MFMA_STEP(0);
        STAGE(B, 1);
        if (kk + 128 < kend) GLOAD(A, kk + 128);
        __syncthreads();
        MFMA_STEP(1);
        if (kk + 128 < kend) {
            STAGE(A, 0);
            if (kk + 192 < kend) GLOAD(B, kk + 192);
            __syncthreads();
        }
    }
#undef GLOAD
#undef STAGE
#undef MFMA_STEP

    float* Cp = P + (long)(ksi * 4 + b) * 524288;
#pragma unroll
    for (int mf = 0; mf < 2; ++mf) {
        const int rb = m0 + wm + mf * 16 + kb * 4;
#pragma unroll
        for (int nf = 0; nf < 2; ++nf) {
            const int col = wn + nf * 16 + lr;
#pragma unroll
            for (int i = 0; i < 4; ++i)
                Cp[(long)(rb + i) * 128 + col] = acc[mf][nf][i];
        }
    }
}

// ---------------------------------------------------------------------------
template <int KS>
static void run_all(const float* incident, const float* degree_v, const float* degree_e,
                    const float* x, const int* e_masks, const float* mlp_W,
                    const float* mlp_b, const float* theta, const float* epsp,
                    const float* bng, const float* bnb, const float* bnm,
                    const float* bnv, float* out, float* ws, hipStream_t stream) {
    float* xw  = ws;                        // 2M floats
    float* hxw = ws + 2097152;              // 2M
    float* t1  = ws + 4194304;              // 2M
    float* Pd  = ws + 6291456;              // KS*2M
    float* Psum = Pd + (long)KS * 2097152;  // 2M
    float* tail = Psum + 2097152;
    u64* rowmask = (u64*)tail;                      // 1M u64
    u64* colmask = rowmask + 1048576;               // 1M u64
    ushort* rowidx = (ushort*)(colmask + 1048576);  // 16384*CAP u16
    ushort* colidx = rowidx + 16384 * CAP;
    int* rowcnt = (int*)(colidx + 16384 * CAP);     // 16K int
    int* colcnt = rowcnt + 16384;
    float* xt  = (float*)(colcnt + 16384);
    float* hxt = xt + 16384;
    float* att = hxt + 16384;

    mlp_k<<<512, 256, 0, stream>>>(x, mlp_W, mlp_b, theta, xw, xt);
    bmask2_k<<<dim3(1024, 4), 256, 0, stream>>>(incident, rowmask);
    btrans_k<<<dim3(64, 64, 4), 64, 0, stream>>>(rowmask, colmask);
    lists_k<<<dim3(1024, 4), 256, 0, stream>>>(rowmask, rowidx, rowcnt);
    lists_k<<<dim3(1024, 4), 256, 0, stream>>>(colmask, colidx, colcnt);

    // G1: hxw = Ht @ xw  (+ hxt = Ht @ xt)
    gatherE_k<false, false, true, false><<<4096, 256, 0, stream>>>(
        colidx, colcnt, colmask, xw, nullptr, att, xt, nullptr,
        nullptr, nullptr, nullptr, nullptr, hxw, hxt);
    softmax_k<<<4, 1024, 0, stream>>>(hxt, e_masks, att);
    // G2: t1 = incident @ (attn * hxw)
    gatherE_k<true, false, false, false><<<4096, 256, 0, stream>>>(
        rowidx, rowcnt, rowmask, hxw, nullptr, att, xt, nullptr,
        nullptr, nullptr, nullptr, nullptr, t1, nullptr);
    // G3: Pd = degree_v @ t1
    gemm_dense<KS><<<32 * KS * 4, 1024, 0, stream>>>(degree_v, t1, Pd);
    const float* g4src = Pd;
    if (KS == 2) { pairsum_k<<<2048, 256, 0, stream>>>(Pd, Psum); g4src = Psum; }
    // G4: t1 = Ht @ sum(Pd)
    gatherE_k<false, false, false, false><<<4096, 256, 0, stream>>>(
        colidx, colcnt, colmask, g4src, nullptr, att, xt, nullptr,
        nullptr, nullptr, nullptr, nullptr, t1, nullptr);
    // G5: Pd = degree_e @ t1
    gemm_dense<KS><<<32 * KS * 4, 1024, 0, stream>>>(degree_e, t1, Pd);
    const float* g6src = Pd;
    if (KS == 2) { pairsum_k<<<2048, 256, 0, stream>>>(Pd, Psum); g6src = Psum; }
    // G6: out = BN(leaky(incident @ (sum(Pd) + eps*hxw)))
    gatherE_k<false, true, false, true><<<4096, 256, 0, stream>>>(
        rowidx, rowcnt, rowmask, g6src, hxw, att, xt, epsp,
        bng, bnb, bnm, bnv, out, nullptr);
}

extern "C" void kernel_launch(void* const* d_in, const int* in_sizes, int n_in,
                              void* d_out, int out_size, void* d_ws, size_t ws_size,
                              hipStream_t stream) {
    const float* incident = (const float*)d_in[0];
    const float* degree_v = (const float*)d_in[1];
    const float* degree_e = (const float*)d_in[2];
    const float* x        = (const float*)d_in[3];
    const int*   e_masks  = (const int*)d_in[4];
    const float* mlp_W    = (const float*)d_in[5];
    const float* mlp_b    = (const float*)d_in[6];
    const float* theta    = (const float*)d_in[7];
    const float* epsp     = (const float*)d_in[8];
    const float* bng      = (const float*)d_in[9];
    const float* bnb      = (const float*)d_in[10];
    const float* bnm      = (const float*)d_in[11];
    const float* bnv      = (const float*)d_in[12];
    float* out = (float*)d_out;
    float* ws = (float*)d_ws;

    if (ws_size >= 95000000ull)
        run_all<2>(incident, degree_v, degree_e, x, e_masks, mlp_W, mlp_b, theta,
                   epsp, bng, bnb, bnm, bnv, out, ws, stream);
    else
        run_all<1>(incident, degree_v, degree_e, x, e_masks, mlp_W, mlp_b, theta,
                   epsp, bng, bnb, bnm, bnv, out, ws, stream);
}

// Round 13
// 403.953 us; speedup vs baseline: 1.2090x; 1.0673x over previous
//
#include <hip/hip_runtime.h>

// HGNN layer, B=4, N=E=4096, D=128, fp32 in/out.
// Round 13: gather overhaul — 8-edge rounds with index double-buffer prefetch,
// all gathers reduced to plain form (attn pre-scaled into hxw_s; eps*hxw folded
// into pairsum), row-lists fused into bmask. GEMM frozen at R12 (XCD-affinity).

typedef __bf16 bf16;
typedef bf16 bf16x8 __attribute__((ext_vector_type(8)));
typedef float f32x4 __attribute__((ext_vector_type(4)));
typedef unsigned long long u64;
typedef unsigned short u16;
typedef u16 u16x8 __attribute__((ext_vector_type(8)));

#define LDK 72  // LDS row stride in bf16 elems
#define SWZ(r, c) ((c) ^ ((((r) >> 3) & 7) << 3))
#define CAP 192

union BPack { bf16 h[2]; unsigned int u; };
static __device__ __forceinline__ bf16 tob(float f) { return (bf16)f; }

// ---------------------------------------------------------------------------
// K1: x_w = x @ mlp_W + mlp_b, fused xt = x @ theta.
__global__ __launch_bounds__(256) void mlp_k(const float* __restrict__ x,
                                             const float* __restrict__ W,
                                             const float* __restrict__ bias,
                                             const float* __restrict__ theta,
                                             float* __restrict__ xw,
                                             float* __restrict__ xt) {
    __shared__ float Ws[32][128];
    __shared__ float xs[32][128];
    const int t = threadIdx.x;
    const long r0 = (long)blockIdx.x * 32;

    for (int i = t * 4; i < 4096; i += 1024)
        *(float4*)&xs[i >> 7][i & 127] = *(const float4*)&x[r0 * 128 + i];

    const int d = t & 127;
    const int rg = (t >> 7) * 16;
    float acc[16];
#pragma unroll
    for (int r = 0; r < 16; ++r) acc[r] = 0.f;

    for (int kk = 0; kk < 128; kk += 32) {
        __syncthreads();
        for (int i = t * 4; i < 4096; i += 1024)
            *(float4*)&Ws[i >> 7][i & 127] =
                *(const float4*)&W[(kk + (i >> 7)) * 128 + (i & 127)];
        __syncthreads();
        for (int k = 0; k < 32; ++k) {
            float w = Ws[k][d];
#pragma unroll
            for (int r = 0; r < 16; ++r) acc[r] += xs[rg + r][kk + k] * w;
        }
    }
    const float bd = bias[d];
#pragma unroll
    for (int r = 0; r < 16; ++r)
        xw[(r0 + rg + r) * 128 + d] = acc[r] + bd;

    if (t < 32) {
        float s = 0.f;
        for (int k = 0; k < 128; ++k) s += xs[t][k] * theta[k];
        xt[r0 + t] = s;
    }
}

// ---------------------------------------------------------------------------
// Row bitmask + fused ELL row-list build. One wave per row; lane l owns
// columns [l*64,(l+1)*64) via 16 independent float4 loads; then in-wave
// prefix scan writes the ascending index list.
__global__ __launch_bounds__(256) void bmask_lists_k(const float* __restrict__ inc,
                                                     u64* __restrict__ rowmask,
                                                     u16* __restrict__ idx,
                                                     int* __restrict__ cnts) {
    const int b = blockIdx.y;
    const int n = blockIdx.x * 4 + (threadIdx.x >> 6);
    const int l = threadIdx.x & 63;
    const float* p = inc + ((long)b << 24) + (long)n * 4096 + l * 64;
    u64 w = 0;
#pragma unroll
    for (int j = 0; j < 16; ++j) {
        const float4 v = *(const float4*)(p + j * 4);
        w |= (u64)(v.x != 0.f ? 1u : 0u) << (4 * j);
        w |= (u64)(v.y != 0.f ? 1u : 0u) << (4 * j + 1);
        w |= (u64)(v.z != 0.f ? 1u : 0u) << (4 * j + 2);
        w |= (u64)(v.w != 0.f ? 1u : 0u) << (4 * j + 3);
    }
    const long rowid = (long)b * 4096 + n;
    rowmask[rowid * 64 + l] = w;

    const int pc = __popcll(w);
    int pre = pc;
#pragma unroll
    for (int o = 1; o < 64; o <<= 1) {
        int t = __shfl_up(pre, o);
        if (l >= o) pre += t;
    }
    if (l == 63) cnts[rowid] = pre;
    u16* op = idx + rowid * CAP;
    int k = pre - pc;
    u64 m = w;
    while (m) {
        const int bit = __builtin_ctzll(m);
        m &= m - 1;
        if (k < CAP) op[k] = (u16)(l * 64 + bit);
        ++k;
    }
}

// 64x64 bit-tile transpose (incident masks).
__global__ void btrans_k(const u64* __restrict__ rowmask, u64* __restrict__ colmask) {
    const int tn = blockIdx.x, te = blockIdx.y, b = blockIdx.z;
    const int l = threadIdx.x;
    __shared__ u64 w[64];
    w[l] = rowmask[((long)b * 4096 + tn * 64 + l) * 64 + te];
    __syncthreads();
    u64 o = 0;
#pragma unroll 8
    for (int j = 0; j < 64; ++j) o |= ((w[j] >> l) & 1ull) << j;
    colmask[((long)b * 4096 + te * 64 + l) * 64 + tn] = o;
}

// ---------------------------------------------------------------------------
// ELL list build from a mask (colmask path).
__global__ __launch_bounds__(256) void lists_k(const u64* __restrict__ mask,
                                               u16* __restrict__ idx,
                                               int* __restrict__ cnts) {
    const int b = blockIdx.y;
    const int r = blockIdx.x * 4 + (threadIdx.x >> 6);
    const int l = threadIdx.x & 63;
    u64 m = mask[((long)b * 4096 + r) * 64 + l];
    const int pc = __popcll(m);
    int pre = pc;
#pragma unroll
    for (int o = 1; o < 64; o <<= 1) {
        int t = __shfl_up(pre, o);
        if (l >= o) pre += t;
    }
    if (l == 63) cnts[b * 4096 + r] = pre;
    u16* op = idx + ((long)b * 4096 + r) * CAP;
    int k = pre - pc;
    while (m) {
        const int bit = __builtin_ctzll(m);
        m &= m - 1;
        if (k < CAP) op[k] = (u16)(l * 64 + bit);
        ++k;
    }
}

// ---------------------------------------------------------------------------
// masked softmax over E per batch.
__global__ void softmax_k(const float* __restrict__ sc, const int* __restrict__ mask,
                          float* __restrict__ attn) {
    const int b = blockIdx.x, t = threadIdx.x;
    __shared__ float red[1024];
    const float* sb = sc + b * 4096;
    const int* mb = mask + b * 4096;

    float mx = -1e30f;
    for (int e = t; e < 4096; e += 1024)
        if (mb[e] != 0) mx = fmaxf(mx, sb[e]);
    red[t] = mx;
    __syncthreads();
    for (int st = 512; st > 0; st >>= 1) {
        if (t < st) red[t] = fmaxf(red[t], red[t + st]);
        __syncthreads();
    }
    mx = red[0];
    __syncthreads();

    float sum = 0.f;
    for (int e = t; e < 4096; e += 1024)
        if (mb[e] != 0) sum += expf(sb[e] - mx);
    red[t] = sum;
    __syncthreads();
    for (int st = 512; st > 0; st >>= 1) {
        if (t < st) red[t] += red[t + st];
        __syncthreads();
    }
    const float inv = 1.f / red[0];
    for (int e = t; e < 4096; e += 1024)
        attn[b * 4096 + e] = (mb[e] != 0) ? expf(sb[e] - mx) * inv : 0.f;
}

// ---------------------------------------------------------------------------
// hxw_s = attn (per edge row) * hxw.  524288 float4 total.
__global__ __launch_bounds__(256) void scale_k(const float* __restrict__ hxw,
                                               const float* __restrict__ att,
                                               float* __restrict__ outp) {
    const long i4 = (long)blockIdx.x * 256 + threadIdx.x;
    float4 v = ((const float4*)hxw)[i4];
    const float s = att[i4 >> 5];
    v.x *= s; v.y *= s; v.z *= s; v.w *= s;
    ((float4*)outp)[i4] = v;
}

// ---------------------------------------------------------------------------
// Sum of split-K partials, optional +eps*H:  O = P0 [+ P1] [+ eps*H].
template <int KSP, bool EPS>
__global__ __launch_bounds__(256) void pairsum_k(const float* __restrict__ P,
                                                 const float* __restrict__ H,
                                                 const float* __restrict__ epsp,
                                                 float* __restrict__ O) {
    const long i4 = (long)blockIdx.x * 256 + threadIdx.x;
    float4 a = ((const float4*)P)[i4];
    if (KSP == 2) {
        float4 c = ((const float4*)P)[i4 + 524288];
        a.x += c.x; a.y += c.y; a.z += c.z; a.w += c.w;
    }
    if (EPS) {
        const float e = epsp[0];
        float4 h = ((const float4*)H)[i4];
        a.x += e * h.x; a.y += e * h.y; a.z += e * h.z; a.w += e * h.w;
    }
    ((float4*)O)[i4] = a;
}

// ---------------------------------------------------------------------------
// Plain ELL gather, 8-edge rounds with index double-buffer prefetch.
// XCD-affinity: slot=bid&7, batch=slot>>1. out[r,:] = sum_e src[e,:].
// HXT: hxt[r] = sum_e xt[e].  EPI: leaky-relu + BN.
template <bool HXT, bool EPI>
__global__ __launch_bounds__(256) void gatherE_k(
    const u16* __restrict__ idx, const int* __restrict__ cnts,
    const u64* __restrict__ mask, const float* __restrict__ src,
    const float* __restrict__ xt,
    const float* __restrict__ bng, const float* __restrict__ bnb,
    const float* __restrict__ bnm, const float* __restrict__ bnv,
    float* __restrict__ out, float* __restrict__ hxt) {
    const int bid = blockIdx.x;
    const int slot = bid & 7;
    const int b = slot >> 1;
    const int chunk = (bid >> 3) * 2 + (slot & 1);
    const int r = chunk * 4 + (threadIdx.x >> 6);
    const int l = threadIdx.x & 63;
    const long rowid = (long)b * 4096 + r;
    const int cnt = cnts[rowid];
    const u16* ip = idx + rowid * CAP;
    const float* S = src + (long)b * 524288;
    const float* xb = xt + (long)b * 4096;
    const int c0 = 2 * l;

    float ax0 = 0.f, ax1 = 0.f, ax2 = 0.f, ax3 = 0.f;
    float ax4 = 0.f, ax5 = 0.f, ax6 = 0.f, ax7 = 0.f;
    float ay0 = 0.f, ay1 = 0.f, ay2 = 0.f, ay3 = 0.f;
    float ay4 = 0.f, ay5 = 0.f, ay6 = 0.f, ay7 = 0.f;
    float hacc = 0.f;

    const int n = cnt < CAP ? cnt : CAP;
    int i = 0;
    if (n >= 8) {
        u16x8 ia = *(const u16x8*)ip;
        for (; i + 8 <= n; i += 8) {
            const int e0 = ia[0], e1 = ia[1], e2 = ia[2], e3 = ia[3];
            const int e4 = ia[4], e5 = ia[5], e6 = ia[6], e7 = ia[7];
            const float2 v0 = *(const float2*)(S + (long)e0 * 128 + c0);
            const float2 v1 = *(const float2*)(S + (long)e1 * 128 + c0);
            const float2 v2 = *(const float2*)(S + (long)e2 * 128 + c0);
            const float2 v3 = *(const float2*)(S + (long)e3 * 128 + c0);
            const float2 v4 = *(const float2*)(S + (long)e4 * 128 + c0);
            const float2 v5 = *(const float2*)(S + (long)e5 * 128 + c0);
            const float2 v6 = *(const float2*)(S + (long)e6 * 128 + c0);
            const float2 v7 = *(const float2*)(S + (long)e7 * 128 + c0);
            const bool more = (i + 16 <= n);
            u16x8 ib;
            if (more) ib = *(const u16x8*)(ip + i + 8);
            if (HXT)
                hacc += ((xb[e0] + xb[e1]) + (xb[e2] + xb[e3])) +
                        ((xb[e4] + xb[e5]) + (xb[e6] + xb[e7]));
            ax0 += v0.x; ay0 += v0.y; ax1 += v1.x; ay1 += v1.y;
            ax2 += v2.x; ay2 += v2.y; ax3 += v3.x; ay3 += v3.y;
            ax4 += v4.x; ay4 += v4.y; ax5 += v5.x; ay5 += v5.y;
            ax6 += v6.x; ay6 += v6.y; ax7 += v7.x; ay7 += v7.y;
            if (more) ia = ib;
        }
    }
    for (; i < n; ++i) {
        const int e = ip[i];
        const float2 v = *(const float2*)(S + (long)e * 128 + c0);
        if (HXT) hacc += xb[e];
        ax0 += v.x; ay0 += v.y;
    }

    if (cnt > CAP) {  // astronomically rare; exact fallback
        const u64 wrd = mask[rowid * 64 + l];
        int seen = 0;
        for (int wi = 0; wi < 64; ++wi) {
            u64 m = __shfl(wrd, wi);
            const int pc = __popcll(m);
            if (seen + pc > CAP) {
                int tk = CAP - seen;
                if (tk < 0) tk = 0;
                for (int t = 0; t < tk; ++t) m &= m - 1;
                while (m) {
                    const int bit = __builtin_ctzll(m);
                    m &= m - 1;
                    const int e = (wi << 6) + bit;
                    const float2 v = *(const float2*)(S + (long)e * 128 + c0);
                    if (HXT) hacc += xb[e];
                    ax0 += v.x; ay0 += v.y;
                }
            }
            seen += pc;
        }
    }

    float ax = ((ax0 + ax1) + (ax2 + ax3)) + ((ax4 + ax5) + (ax6 + ax7));
    float ay = ((ay0 + ay1) + (ay2 + ay3)) + ((ay4 + ay5) + (ay6 + ay7));
    if (EPI) {
        float t0 = (ax >= 0.f) ? ax : 0.01f * ax;
        float t1 = (ay >= 0.f) ? ay : 0.01f * ay;
        ax = (t0 - bnm[c0]) * rsqrtf(bnv[c0] + 1e-5f) * bng[c0] + bnb[c0];
        ay = (t1 - bnm[c0 + 1]) * rsqrtf(bnv[c0 + 1] + 1e-5f) * bng[c0 + 1] + bnb[c0 + 1];
    }
    *(float2*)&out[(long)b * 524288 + (long)r * 128 + c0] = (float2){ax, ay};
    if (HXT && l == 0) hxt[rowid] = hacc;
}

// ---------------------------------------------------------------------------
// Dense bf16-MFMA GEMM (R12, frozen): 128x128 tile, 1024 thr = 16 waves,
// BK=64, LDS dbuf, 2 named reg sets, 1 barrier/phase, XCD-affinity 1D grid.
template <int KS>
__global__ __launch_bounds__(1024, 4) void gemm_dense(
    const float* __restrict__ A, const float* __restrict__ Bsrc,
    float* __restrict__ P) {
    __shared__ __align__(16) bf16 As[2][128][LDK];
    __shared__ __align__(16) bf16 Bs[2][128][LDK];

    const int tid = threadIdx.x;
    const int bid = blockIdx.x;
    const int slot = bid & 7;
    const int b = slot >> 1;
    const int sub = (bid >> 3) * 2 + (slot & 1);
    const int ksi = sub % KS;
    const int m0 = (sub / KS) * 128;
    constexpr int KCH = 4096 / KS;
    const int kbeg = ksi * KCH, kend = kbeg + KCH;
    const long Aoff = (long)b << 24;
    const long Boff = (long)b * 524288;

    const int wave = tid >> 6, lane = tid & 63;
    const int lr = lane & 15, kb = lane >> 4;
    const int wm = (wave >> 2) * 32, wn = (wave & 3) * 32;

    const int ar = tid >> 3, ak = (tid & 7) * 8;
    const int bd4 = (tid & 31) * 4, bk2 = (tid >> 5) * 2;

    const float* Abase = A + Aoff + (long)(m0 + ar) * 4096 + ak;
    const float* Bbase = Bsrc + Boff + (long)bk2 * 128 + bd4;

    f32x4 acc[2][2];
#pragma unroll
    for (int mf = 0; mf < 2; ++mf)
#pragma unroll
        for (int nf = 0; nf < 2; ++nf) acc[mf][nf] = (f32x4){0.f, 0.f, 0.f, 0.f};

    float4 pa0A, pa1A, pb0A, pb1A;
    float4 pa0B, pa1B, pb0B, pb1B;

#define GLOAD(S, kk)                                                        \
    {                                                                       \
        const float* ga = Abase + (kk);                                     \
        pa0##S = *(const float4*)ga;                                        \
        pa1##S = *(const float4*)(ga + 4);                                  \
        const float* gb = Bbase + (long)(kk) * 128;                         \
        pb0##S = *(const float4*)gb;                                        \
        pb1##S = *(const float4*)(gb + 128);                                \
    }

#define STAGE(S, bu)                                                        \
    {                                                                       \
        bf16x8 p;                                                           \
        p[0] = tob(pa0##S.x); p[1] = tob(pa0##S.y); p[2] = tob(pa0##S.z); p[3] = tob(pa0##S.w); \
        p[4] = tob(pa1##S.x); p[5] = tob(pa1##S.y); p[6] = tob(pa1##S.z); p[7] = tob(pa1##S.w); \
        *(bf16x8*)&As[bu][ar][SWZ(ar, ak)] = p;                             \
        float va[4] = {pb0##S.x, pb0##S.y, pb0##S.z, pb0##S.w};             \
        float vb[4] = {pb1##S.x, pb1##S.y, pb1##S.z, pb1##S.w};             \
        _Pragma("unroll")                                                   \
        for (int j = 0; j < 4; ++j) {                                       \
            BPack q; q.h[0] = tob(va[j]); q.h[1] = tob(vb[j]);              \
            *(unsigned int*)&Bs[bu][bd4 + j][SWZ(bd4 + j, bk2)] = q.u;      \
        }                                                                   \
    }

#define MFMA_STEP(bu)                                                       \
    {                                                                       \
        _Pragma("unroll")                                                   \
        for (int ks = 0; ks < 2; ++ks) {                                    \
            const int ka = ks * 32 + kb * 8;                                \
            bf16x8 af[2], bfr[2];                                           \
            _Pragma("unroll")                                               \
            for (int mf = 0; mf < 2; ++mf) {                                \
                const int rA = wm + mf * 16 + lr;                           \
                af[mf] = *(const bf16x8*)&As[bu][rA][SWZ(rA, ka)];          \
            }                                                               \
            _Pragma("unroll")                                               \
            for (int nf = 0; nf < 2; ++nf) {                                \
                const int rB = wn + nf * 16 + lr;                           \
                bfr[nf] = *(const bf16x8*)&Bs[bu][rB][SWZ(rB, ka)];         \
            }                                                               \
            _Pragma("unroll")                                               \
            for (int mf = 0; mf < 2; ++mf)                                  \
                _Pragma("unroll")                                           \
                for (int nf = 0; nf < 2; ++nf)                              \
                    acc[mf][nf] = __builtin_amdgcn_mfma_f32_16x16x32_bf16(  \
                        af[mf], bfr[nf], acc[mf][nf], 0, 0, 0);             \
        }                                                                   \
    }

    GLOAD(A, kbeg);
    GLOAD(B, kbeg + 64);
    STAGE(A, 0);
    __syncthreads();

    for (int kk = kbeg; kk < kend; kk += 128) {
        MFMA_STEP(0);
        STAGE(B, 1);
        if (kk + 128 < kend) GLOAD(A, kk + 128);
        __syncthreads();
        MFMA_STEP(1);
        if (kk + 128 < kend) {
            STAGE(A, 0);
            if (kk + 192 < kend) GLOAD(B, kk + 192);
            __syncthreads();
        }
    }
#undef GLOAD
#undef STAGE
#undef MFMA_STEP

    float* Cp = P + (long)(ksi * 4 + b) * 524288;
#pragma unroll
    for (int mf = 0; mf < 2; ++mf) {
        const int rb = m0 + wm + mf * 16 + kb * 4;
#pragma unroll
        for (int nf = 0; nf < 2; ++nf) {
            const int col = wn + nf * 16 + lr;
#pragma unroll
            for (int i = 0; i < 4; ++i)
                Cp[(long)(rb + i) * 128 + col] = acc[mf][nf][i];
        }
    }
}

// ---------------------------------------------------------------------------
template <int KS>
static void run_all(const float* incident, const float* degree_v, const float* degree_e,
                    const float* x, const int* e_masks, const float* mlp_W,
                    const float* mlp_b, const float* theta, const float* epsp,
                    const float* bng, const float* bnb, const float* bnm,
                    const float* bnv, float* out, float* ws, hipStream_t stream) {
    float* xw    = ws;                        // 2M floats
    float* hxw   = ws + 2097152;              // 2M
    float* hxw_s = ws + 4194304;              // 2M
    float* t1    = ws + 6291456;              // 2M
    float* Pd    = ws + 8388608;              // KS*2M
    float* Psum  = Pd + (long)KS * 2097152;   // 2M
    float* tail  = Psum + 2097152;
    u64* rowmask = (u64*)tail;                       // 1M u64
    u64* colmask = rowmask + 1048576;                // 1M u64
    u16* rowidx = (u16*)(colmask + 1048576);         // 16384*CAP u16
    u16* colidx = rowidx + 16384 * CAP;
    int* rowcnt = (int*)(colidx + 16384 * CAP);      // 16K int
    int* colcnt = rowcnt + 16384;
    float* xt  = (float*)(colcnt + 16384);
    float* hxt = xt + 16384;
    float* att = hxt + 16384;

    mlp_k<<<512, 256, 0, stream>>>(x, mlp_W, mlp_b, theta, xw, xt);
    bmask_lists_k<<<dim3(1024, 4), 256, 0, stream>>>(incident, rowmask, rowidx, rowcnt);
    btrans_k<<<dim3(64, 64, 4), 64, 0, stream>>>(rowmask, colmask);
    lists_k<<<dim3(1024, 4), 256, 0, stream>>>(colmask, colidx, colcnt);

    // G1: hxw = Ht @ xw  (+ hxt = Ht @ xt)
    gatherE_k<true, false><<<4096, 256, 0, stream>>>(
        colidx, colcnt, colmask, xw, xt, nullptr, nullptr, nullptr, nullptr,
        hxw, hxt);
    softmax_k<<<4, 1024, 0, stream>>>(hxt, e_masks, att);
    scale_k<<<2048, 256, 0, stream>>>(hxw, att, hxw_s);
    // G2: t1 = incident @ hxw_s
    gatherE_k<false, false><<<4096, 256, 0, stream>>>(
        rowidx, rowcnt, rowmask, hxw_s, xt, nullptr, nullptr, nullptr, nullptr,
        t1, nullptr);
    // G3: Pd = degree_v @ t1
    gemm_dense<KS><<<32 * KS * 4, 1024, 0, stream>>>(degree_v, t1, Pd);
    pairsum_k<KS, false><<<2048, 256, 0, stream>>>(Pd, nullptr, nullptr, Psum);
    // G4: t1 = Ht @ Psum
    gatherE_k<false, false><<<4096, 256, 0, stream>>>(
        colidx, colcnt, colmask, Psum, xt, nullptr, nullptr, nullptr, nullptr,
        t1, nullptr);
    // G5: Pd = degree_e @ t1
    gemm_dense<KS><<<32 * KS * 4, 1024, 0, stream>>>(degree_e, t1, Pd);
    pairsum_k<KS, true><<<2048, 256, 0, stream>>>(Pd, hxw, epsp, Psum);
    // G6: out = BN(leaky(incident @ Psum))
    gatherE_k<false, true><<<4096, 256, 0, stream>>>(
        rowidx, rowcnt, rowmask, Psum, xt, bng, bnb, bnm, bnv, out, nullptr);
}

extern "C" void kernel_launch(void* const* d_in, const int* in_sizes, int n_in,
                              void* d_out, int out_size, void* d_ws, size_t ws_size,
                              hipStream_t stream) {
    const float* incident = (const float*)d_in[0];
    const float* degree_v = (const float*)d_in[1];
    const float* degree_e = (const float*)d_in[2];
    const float* x        = (const float*)d_in[3];
    const int*   e_masks  = (const int*)d_in[4];
    const float* mlp_W    = (const float*)d_in[5];
    const float* mlp_b    = (const float*)d_in[6];
    const float* theta    = (const float*)d_in[7];
    const float* epsp     = (const float*)d_in[8];
    const float* bng      = (const float*)d_in[9];
    const float* bnb      = (const float*)d_in[10];
    const float* bnm      = (const float*)d_in[11];
    const float* bnv      = (const float*)d_in[12];
    float* out = (float*)d_out;
    float* ws = (float*)d_ws;

    if (ws_size >= 110000000ull)
        run_all<2>(incident, degree_v, degree_e, x, e_masks, mlp_W, mlp_b, theta,
                   epsp, bng, bnb, bnm, bnv, out, ws, stream);
    else
        run_all<1>(incident, degree_v, degree_e, x, e_masks, mlp_W, mlp_b, theta,
                   epsp, bng, bnb, bnm, bnv, out, ws, stream);
}